// Round 3
// baseline (87.572 us; speedup 1.0000x reference)
//
#include <hip/hip_runtime.h>
#include <math.h>

#define RAD2DEG 57.29577951308232f
#define INV360  (1.0f/360.0f)
#define TINYV   1e-6f

// sin/cos of (rev revolutions): hw v_sin/v_cos take revolutions; one fract
// range-reduction keeps us in the accurate domain.
__device__ __forceinline__ void sincos_rev(float rev, float* s, float* c) {
    float r = rev - floorf(rev);
    *s = __builtin_amdgcn_sinf(r);
    *c = __builtin_amdgcn_cosf(r);
}

// Octant-reduced atan2, 6-term minimax poly on [0,1]; max err ~1e-6 rad.
__device__ __forceinline__ float fast_atan2f(float y, float x) {
    float ax = fabsf(x), ay = fabsf(y);
    float mx = fmaxf(ax, ay), mn = fminf(ax, ay);
    float q = mn * __builtin_amdgcn_rcpf(mx);
    q = (mx == 0.0f) ? 0.0f : q;          // atan2(0,0) = 0
    float s = q * q;
    float p =        -0.0117212f;
    p = fmaf(p, s,  0.05265332f);
    p = fmaf(p, s, -0.11643287f);
    p = fmaf(p, s,  0.19354346f);
    p = fmaf(p, s, -0.33262347f);
    p = fmaf(p, s,  0.99997726f);
    float r = p * q;
    r = (ay > ax)  ? (1.57079632679f - r) : r;
    r = (x < 0.0f) ? (3.14159265359f - r) : r;
    return copysignf(r, y);
}

// 4 rows per thread: 96B per thread = 6 aligned float4 loads/stores,
// wave-uniform DH trig amortized 4x.
__global__ __launch_bounds__(256) void fk_kernel(const float* __restrict__ theta,
                                                 const float* __restrict__ dh,
                                                 float* __restrict__ out,
                                                 int Bquads) {
    int p = blockIdx.x * blockDim.x + threadIdx.x;
    if (p >= Bquads) return;

    const float4* tp = (const float4*)(theta + (size_t)p * 24);
    float4 f[6];
    #pragma unroll
    for (int i = 0; i < 6; ++i) f[i] = tp[i];
    const float* tf = (const float*)f;   // unrolled -> stays in registers

    // wave-uniform DH-derived constants
    float a_[6], sa[6], ca[6], sad[6], cad[6], offr[6];
    #pragma unroll
    for (int i = 0; i < 6; ++i) {
        a_[i]   = dh[i*4+0];
        float d = dh[i*4+2];
        offr[i] = dh[i*4+3] * INV360;
        float sA, cA;
        sincos_rev(dh[i*4+1] * INV360, &sA, &cA);
        sa[i] = sA; ca[i] = cA;
        sad[i] = -sA * d;   // row1 translation term
        cad[i] =  cA * d;   // row2 translation term
    }

    float res[24];

    #pragma unroll
    for (int rr = 0; rr < 4; ++rr) {
        float T00,T01,T02,T03, T10,T11,T12,T13, T20,T21,T22,T23;
        {
            float s, c;
            sincos_rev(fmaf(tf[rr*6 + 0], INV360, offr[0]), &s, &c);
            T00 = c;         T01 = -s;         T02 = 0.f;     T03 = a_[0];
            T10 = s * ca[0]; T11 = c * ca[0];  T12 = -sa[0];  T13 = sad[0];
            T20 = s * sa[0]; T21 = c * sa[0];  T22 = ca[0];   T23 = cad[0];
        }
        #pragma unroll
        for (int i = 1; i < 6; ++i) {
            float s, c;
            sincos_rev(fmaf(tf[rr*6 + i], INV360, offr[i]), &s, &c);
            float sca = s * ca[i], cca = c * ca[i];
            float ssa = s * sa[i], csa = c * sa[i];
            float n0, n1, n2, n3;
            n0 =  T00*c + T01*sca + T02*ssa;
            n1 = -T00*s + T01*cca + T02*csa;
            n2 =          -T01*sa[i] + T02*ca[i];
            n3 =  T00*a_[i] + T01*sad[i] + T02*cad[i] + T03;
            T00=n0; T01=n1; T02=n2; T03=n3;
            n0 =  T10*c + T11*sca + T12*ssa;
            n1 = -T10*s + T11*cca + T12*csa;
            n2 =          -T11*sa[i] + T12*ca[i];
            n3 =  T10*a_[i] + T11*sad[i] + T12*cad[i] + T13;
            T10=n0; T11=n1; T12=n2; T13=n3;
            n0 =  T20*c + T21*sca + T22*ssa;
            n1 = -T20*s + T21*cca + T22*csa;
            n2 =          -T21*sa[i] + T22*ca[i];
            n3 =  T20*a_[i] + T21*sad[i] + T22*cad[i] + T23;
            T20=n0; T21=n1; T22=n2; T23=n3;
        }

        bool cond = (fabsf(T12) <= TINYV) && (fabsf(T22) <= TINYV);
        // cos(A2)*T00 - sin(A2)*T01 == hypot(T00,T01) -> no sincos needed
        float A  = fast_atan2f(-T01, T00) * RAD2DEG;
        float Bd = fast_atan2f(T02, __builtin_amdgcn_sqrtf(fmaf(T00,T00,T01*T01))) * RAD2DEG;
        float C  = fast_atan2f(-T12, T22) * RAD2DEG;
        if (__ballot(cond)) {   // essentially never; wave-uniform skip
            float A1 = fast_atan2f(T10, T11) * RAD2DEG;
            float B1 = fast_atan2f(T02, T22) * RAD2DEG;
            A  = cond ? A1  : A;
            Bd = cond ? B1  : Bd;
            C  = cond ? 0.f : C;
        }
        res[rr*6+0] = T03; res[rr*6+1] = T13; res[rr*6+2] = T23;
        res[rr*6+3] = A;   res[rr*6+4] = Bd;  res[rr*6+5] = C;
    }

    float4* op = (float4*)(out + (size_t)p * 24);
    #pragma unroll
    for (int i = 0; i < 6; ++i)
        op[i] = make_float4(res[i*4+0], res[i*4+1], res[i*4+2], res[i*4+3]);
}

extern "C" void kernel_launch(void* const* d_in, const int* in_sizes, int n_in,
                              void* d_out, int out_size, void* d_ws, size_t ws_size,
                              hipStream_t stream) {
    const float* theta = (const float*)d_in[0];
    const float* dh    = (const float*)d_in[1];
    float* out = (float*)d_out;
    int Bquads = in_sizes[0] / 24;   // 262144 groups of 4 rows
    int block = 256;
    int grid = (Bquads + block - 1) / block;
    fk_kernel<<<grid, block, 0, stream>>>(theta, dh, out, Bquads);
}

// Round 4
// 83.968 us; speedup vs baseline: 1.0429x; 1.0429x over previous
//
#include <hip/hip_runtime.h>
#include <math.h>

#define RAD2DEG 57.29577951308232f
#define INV360  (1.0f/360.0f)
#define TINYV   1e-6f

// sin/cos of (rev revolutions): hw v_sin/v_cos take revolutions; one fract
// range-reduction keeps us in the accurate domain.
__device__ __forceinline__ void sincos_rev(float rev, float* s, float* c) {
    float r = rev - floorf(rev);
    *s = __builtin_amdgcn_sinf(r);
    *c = __builtin_amdgcn_cosf(r);
}

// Octant-reduced atan2, 6-term minimax poly on [0,1]; max err ~1e-6 rad.
__device__ __forceinline__ float fast_atan2f(float y, float x) {
    float ax = fabsf(x), ay = fabsf(y);
    float mx = fmaxf(ax, ay), mn = fminf(ax, ay);
    float q = mn * __builtin_amdgcn_rcpf(mx);
    q = (mx == 0.0f) ? 0.0f : q;          // atan2(0,0) = 0
    float s = q * q;
    float p =        -0.0117212f;
    p = fmaf(p, s,  0.05265332f);
    p = fmaf(p, s, -0.11643287f);
    p = fmaf(p, s,  0.19354346f);
    p = fmaf(p, s, -0.33262347f);
    p = fmaf(p, s,  0.99997726f);
    float r = p * q;
    r = (ay > ax)  ? (1.57079632679f - r) : r;
    r = (x < 0.0f) ? (3.14159265359f - r) : r;
    return copysignf(r, y);
}

// 2 rows per thread: 48B per thread = 3 aligned float4 loads/stores.
// (4 rows/thread measured slower: 87.6 vs 83.3 us — fewer blocks, no gain.)
__global__ __launch_bounds__(256) void fk_kernel(const float* __restrict__ theta,
                                                 const float* __restrict__ dh,
                                                 float* __restrict__ out,
                                                 int Bpairs) {
    int p = blockIdx.x * blockDim.x + threadIdx.x;
    if (p >= Bpairs) return;

    const float4* tp = (const float4*)(theta + (size_t)p * 12);
    float4 f0 = tp[0];
    float4 f1 = tp[1];
    float4 f2 = tp[2];

    // wave-uniform DH-derived constants
    float a_[6], sa[6], ca[6], sad[6], cad[6], offr[6];
    #pragma unroll
    for (int i = 0; i < 6; ++i) {
        a_[i]   = dh[i*4+0];
        float d = dh[i*4+2];
        offr[i] = dh[i*4+3] * INV360;
        float sA, cA;
        sincos_rev(dh[i*4+1] * INV360, &sA, &cA);
        sa[i] = sA; ca[i] = cA;
        sad[i] = -sA * d;   // row1 translation term
        cad[i] =  cA * d;   // row2 translation term
    }

    float th[2][6] = {{f0.x, f0.y, f0.z, f0.w, f1.x, f1.y},
                      {f1.z, f1.w, f2.x, f2.y, f2.z, f2.w}};
    float res[2][6];

    #pragma unroll
    for (int rr = 0; rr < 2; ++rr) {
        float T00,T01,T02,T03, T10,T11,T12,T13, T20,T21,T22,T23;
        {
            float s, c;
            sincos_rev(fmaf(th[rr][0], INV360, offr[0]), &s, &c);
            T00 = c;         T01 = -s;         T02 = 0.f;     T03 = a_[0];
            T10 = s * ca[0]; T11 = c * ca[0];  T12 = -sa[0];  T13 = sad[0];
            T20 = s * sa[0]; T21 = c * sa[0];  T22 = ca[0];   T23 = cad[0];
        }
        #pragma unroll
        for (int i = 1; i < 6; ++i) {
            float s, c;
            sincos_rev(fmaf(th[rr][i], INV360, offr[i]), &s, &c);
            float sca = s * ca[i], cca = c * ca[i];
            float ssa = s * sa[i], csa = c * sa[i];
            float n0, n1, n2, n3;
            n0 =  T00*c + T01*sca + T02*ssa;
            n1 = -T00*s + T01*cca + T02*csa;
            n2 =          -T01*sa[i] + T02*ca[i];
            n3 =  T00*a_[i] + T01*sad[i] + T02*cad[i] + T03;
            T00=n0; T01=n1; T02=n2; T03=n3;
            n0 =  T10*c + T11*sca + T12*ssa;
            n1 = -T10*s + T11*cca + T12*csa;
            n2 =          -T11*sa[i] + T12*ca[i];
            n3 =  T10*a_[i] + T11*sad[i] + T12*cad[i] + T13;
            T10=n0; T11=n1; T12=n2; T13=n3;
            n0 =  T20*c + T21*sca + T22*ssa;
            n1 = -T20*s + T21*cca + T22*csa;
            n2 =          -T21*sa[i] + T22*ca[i];
            n3 =  T20*a_[i] + T21*sad[i] + T22*cad[i] + T23;
            T20=n0; T21=n1; T22=n2; T23=n3;
        }

        bool cond = (fabsf(T12) <= TINYV) && (fabsf(T22) <= TINYV);
        // cos(A2)*T00 - sin(A2)*T01 == hypot(T00,T01) -> no sincos needed
        float A  = fast_atan2f(-T01, T00) * RAD2DEG;
        float Bd = fast_atan2f(T02, __builtin_amdgcn_sqrtf(fmaf(T00,T00,T01*T01))) * RAD2DEG;
        float C  = fast_atan2f(-T12, T22) * RAD2DEG;
        if (__ballot(cond)) {   // essentially never; wave-uniform skip
            float A1 = fast_atan2f(T10, T11) * RAD2DEG;
            float B1 = fast_atan2f(T02, T22) * RAD2DEG;
            A  = cond ? A1  : A;
            Bd = cond ? B1  : Bd;
            C  = cond ? 0.f : C;
        }
        res[rr][0] = T03; res[rr][1] = T13; res[rr][2] = T23;
        res[rr][3] = A;   res[rr][4] = Bd;  res[rr][5] = C;
    }

    float4* op = (float4*)(out + (size_t)p * 12);
    op[0] = make_float4(res[0][0], res[0][1], res[0][2], res[0][3]);
    op[1] = make_float4(res[0][4], res[0][5], res[1][0], res[1][1]);
    op[2] = make_float4(res[1][2], res[1][3], res[1][4], res[1][5]);
}

extern "C" void kernel_launch(void* const* d_in, const int* in_sizes, int n_in,
                              void* d_out, int out_size, void* d_ws, size_t ws_size,
                              hipStream_t stream) {
    const float* theta = (const float*)d_in[0];
    const float* dh    = (const float*)d_in[1];
    float* out = (float*)d_out;
    int Bpairs = in_sizes[0] / 12;   // 524288 pairs of rows
    int block = 256;
    int grid = (Bpairs + block - 1) / block;
    fk_kernel<<<grid, block, 0, stream>>>(theta, dh, out, Bpairs);
}